// Round 1
// baseline (2888.734 us; speedup 1.0000x reference)
//
#include <hip/hip_runtime.h>

#define N_NODES 50000
#define N_EDGES 800000
#define D 256

// ---------------------------------------------------------------------------
// 1. Degree histogram over edge destinations (self-loop +1 folded into dinv).
// ---------------------------------------------------------------------------
__global__ void deg_kernel(const int* __restrict__ ei, int* __restrict__ deg) {
    int e = blockIdx.x * blockDim.x + threadIdx.x;
    if (e < N_EDGES) {
        int d = ei[N_EDGES + e];  // dst row
        if ((unsigned)d < (unsigned)N_NODES) atomicAdd(&deg[d], 1);
    }
}

// ---------------------------------------------------------------------------
// 2. dinv[i] = 1/sqrt(indeg[i] + 1)   (+1 = self-loop; always >= 1)
// ---------------------------------------------------------------------------
__global__ void dinv_kernel(const int* __restrict__ deg, float* __restrict__ dinv) {
    int i = blockIdx.x * blockDim.x + threadIdx.x;
    if (i < N_NODES) dinv[i] = 1.0f / sqrtf((float)(deg[i] + 1));
}

// ---------------------------------------------------------------------------
// 3. h = x @ W^T   (fp32, classic 64x64 tile, BK=16, 256 thr, 4x4 per thread)
// ---------------------------------------------------------------------------
__global__ __launch_bounds__(256) void gemm_kernel(const float* __restrict__ x,
                                                   const float* __restrict__ W,
                                                   float* __restrict__ h) {
    __shared__ float xs[16][65];  // [k][row]
    __shared__ float wt[16][65];  // [k][col]
    const int row0 = blockIdx.x * 64;
    const int col0 = blockIdx.y * 64;
    const int t  = threadIdx.x;
    const int tx = t & 15;        // col group
    const int ty = t >> 4;        // row group
    float acc[4][4] = {{0.f}};

    for (int k0 = 0; k0 < D; k0 += 16) {
#pragma unroll
        for (int j = 0; j < 4; j++) {
            int i  = t + j * 256;         // 0..1023
            int r  = i >> 4;              // 0..63
            int kk = i & 15;
            int rg = row0 + r;
            xs[kk][r] = (rg < N_NODES) ? x[(size_t)rg * D + k0 + kk] : 0.0f;
        }
#pragma unroll
        for (int j = 0; j < 4; j++) {
            int i  = t + j * 256;
            int c  = i >> 4;
            int kk = i & 15;
            wt[kk][c] = W[(size_t)(col0 + c) * D + k0 + kk];
        }
        __syncthreads();
#pragma unroll
        for (int kk = 0; kk < 16; kk++) {
            float a_[4], b_[4];
#pragma unroll
            for (int i = 0; i < 4; i++) a_[i] = xs[kk][ty * 4 + i];
#pragma unroll
            for (int j = 0; j < 4; j++) b_[j] = wt[kk][tx * 4 + j];
#pragma unroll
            for (int i = 0; i < 4; i++)
#pragma unroll
                for (int j = 0; j < 4; j++) acc[i][j] += a_[i] * b_[j];
        }
        __syncthreads();
    }
#pragma unroll
    for (int i = 0; i < 4; i++) {
        int r = row0 + ty * 4 + i;
        if (r < N_NODES) {
#pragma unroll
            for (int j = 0; j < 4; j++)
                h[(size_t)r * D + col0 + tx * 4 + j] = acc[i][j];
        }
    }
}

// ---------------------------------------------------------------------------
// 4. Edge scatter: one wave per edge; out[dst] += h[src] * dinv[s]*dinv[d]
// ---------------------------------------------------------------------------
__global__ __launch_bounds__(256) void scatter_kernel(const int* __restrict__ ei,
                                                      const float* __restrict__ dinv,
                                                      const float* __restrict__ h,
                                                      float* __restrict__ out) {
    int e    = blockIdx.x * 4 + (threadIdx.x >> 6);  // wave index = edge
    int lane = threadIdx.x & 63;
    if (e >= N_EDGES) return;
    int s = ei[e];
    int d = ei[N_EDGES + e];
    if ((unsigned)s >= (unsigned)N_NODES || (unsigned)d >= (unsigned)N_NODES) return;
    float norm = dinv[s] * dinv[d];
    const float4 hv = *reinterpret_cast<const float4*>(&h[(size_t)s * D + lane * 4]);
    float* op = &out[(size_t)d * D + lane * 4];
    atomicAdd(op + 0, hv.x * norm);
    atomicAdd(op + 1, hv.y * norm);
    atomicAdd(op + 2, hv.z * norm);
    atomicAdd(op + 3, hv.w * norm);
}

// ---------------------------------------------------------------------------
// 5. Final blend: out = a*x + (1-a)*(agg + dinv^2*h + b)   (float4 over 12.8M)
// ---------------------------------------------------------------------------
__global__ void final_kernel(const float* __restrict__ x,
                             const float* __restrict__ h,
                             const float* __restrict__ dinv,
                             const float* __restrict__ b,
                             const float* __restrict__ alpha,
                             float* __restrict__ out) {
    int i = blockIdx.x * blockDim.x + threadIdx.x;  // float4 index
    const int TOT = N_NODES * (D / 4);
    if (i >= TOT) return;
    int node = i >> 6;          // D/4 = 64 float4 per node
    int c4   = i & 63;
    float dv  = dinv[node];
    float dv2 = dv * dv;
    float a   = alpha[0];
    float4 xv = reinterpret_cast<const float4*>(x)[i];
    float4 hv = reinterpret_cast<const float4*>(h)[i];
    float4 ov = reinterpret_cast<float4*>(out)[i];
    float4 bv = reinterpret_cast<const float4*>(b)[c4];
    float4 r;
    r.x = a * xv.x + (1.0f - a) * (ov.x + dv2 * hv.x + bv.x);
    r.y = a * xv.y + (1.0f - a) * (ov.y + dv2 * hv.y + bv.y);
    r.z = a * xv.z + (1.0f - a) * (ov.z + dv2 * hv.z + bv.z);
    r.w = a * xv.w + (1.0f - a) * (ov.w + dv2 * hv.w + bv.w);
    reinterpret_cast<float4*>(out)[i] = r;
}

// ---------------------------------------------------------------------------
extern "C" void kernel_launch(void* const* d_in, const int* in_sizes, int n_in,
                              void* d_out, int out_size, void* d_ws, size_t ws_size,
                              hipStream_t stream) {
    const float* x     = (const float*)d_in[0];
    const int*   ei    = (const int*)d_in[1];
    const float* W     = (const float*)d_in[2];
    const float* b     = (const float*)d_in[3];
    const float* alpha = (const float*)d_in[4];
    float* out = (float*)d_out;

    char* ws = (char*)d_ws;
    float* h    = (float*)ws;                                  // 51.2 MB
    int*   deg  = (int*)(ws + (size_t)N_NODES * D * 4);        // 200 KB
    float* dinv = (float*)(ws + (size_t)N_NODES * D * 4 + (size_t)N_NODES * 4);

    hipMemsetAsync(deg, 0, (size_t)N_NODES * 4, stream);
    hipMemsetAsync(out, 0, (size_t)N_NODES * D * 4, stream);

    deg_kernel<<<(N_EDGES + 255) / 256, 256, 0, stream>>>(ei, deg);
    dinv_kernel<<<(N_NODES + 255) / 256, 256, 0, stream>>>(deg, dinv);
    gemm_kernel<<<dim3((N_NODES + 63) / 64, D / 64), 256, 0, stream>>>(x, W, h);
    scatter_kernel<<<(N_EDGES + 3) / 4, 256, 0, stream>>>(ei, dinv, h, out);
    final_kernel<<<(N_NODES * (D / 4) + 255) / 256, 256, 0, stream>>>(x, h, dinv, b, alpha, out);
}

// Round 2
// 460.212 us; speedup vs baseline: 6.2770x; 6.2770x over previous
//
#include <hip/hip_runtime.h>

#define N_NODES 50000
#define N_EDGES 800000
#define D 256

// ---------------------------------------------------------------------------
// 1. Degree histogram over edge destinations.
// ---------------------------------------------------------------------------
__global__ void deg_kernel(const int* __restrict__ ei, int* __restrict__ deg) {
    int e = blockIdx.x * blockDim.x + threadIdx.x;
    if (e < N_EDGES) {
        int d = ei[N_EDGES + e];  // dst row
        if ((unsigned)d < (unsigned)N_NODES) atomicAdd(&deg[d], 1);
    }
}

// ---------------------------------------------------------------------------
// 2. Single-block exclusive scan: row_ptr/cursor = prefix(deg), dinv fused.
// ---------------------------------------------------------------------------
__global__ __launch_bounds__(1024) void scan_kernel(const int* __restrict__ deg,
                                                    int* __restrict__ row_ptr,
                                                    int* __restrict__ cursor,
                                                    float* __restrict__ dinv) {
    __shared__ int tmp[1024];
    __shared__ int carry;
    if (threadIdx.x == 0) carry = 0;
    __syncthreads();
    for (int base = 0; base < N_NODES; base += 1024) {
        int i = base + (int)threadIdx.x;
        int v = (i < N_NODES) ? deg[i] : 0;
        tmp[threadIdx.x] = v;
        __syncthreads();
#pragma unroll
        for (int off = 1; off < 1024; off <<= 1) {
            int t = (threadIdx.x >= (unsigned)off) ? tmp[threadIdx.x - off] : 0;
            __syncthreads();
            tmp[threadIdx.x] += t;
            __syncthreads();
        }
        int incl = tmp[threadIdx.x];
        if (i < N_NODES) {
            int rp = carry + incl - v;   // exclusive
            row_ptr[i] = rp;
            cursor[i]  = rp;
            dinv[i] = rsqrtf((float)(v + 1));   // +1 self-loop
        }
        __syncthreads();
        if (threadIdx.x == 0) carry += tmp[1023];
        __syncthreads();
    }
    if (threadIdx.x == 0) row_ptr[N_NODES] = carry;
}

// ---------------------------------------------------------------------------
// 3. Bucket fill: csr_src[pos] = src for each edge, bucketed by dst.
// ---------------------------------------------------------------------------
__global__ void fill_kernel(const int* __restrict__ ei, int* __restrict__ cursor,
                            int* __restrict__ csr_src) {
    int e = blockIdx.x * blockDim.x + threadIdx.x;
    if (e < N_EDGES) {
        int s = ei[e];
        int d = ei[N_EDGES + e];
        if ((unsigned)d < (unsigned)N_NODES) {
            int pos = atomicAdd(&cursor[d], 1);
            csr_src[pos] = s;
        }
    }
}

// ---------------------------------------------------------------------------
// 4. h = x @ W^T   (fp32, 64x64 tile, BK=16, 256 thr, 4x4 per thread)
// ---------------------------------------------------------------------------
__global__ __launch_bounds__(256) void gemm_kernel(const float* __restrict__ x,
                                                   const float* __restrict__ W,
                                                   float* __restrict__ h) {
    __shared__ float xs[16][65];  // [k][row]
    __shared__ float wt[16][65];  // [k][col]
    const int row0 = blockIdx.x * 64;
    const int col0 = blockIdx.y * 64;
    const int t  = threadIdx.x;
    const int tx = t & 15;
    const int ty = t >> 4;
    float acc[4][4] = {{0.f}};

    for (int k0 = 0; k0 < D; k0 += 16) {
#pragma unroll
        for (int j = 0; j < 4; j++) {
            int i  = t + j * 256;
            int r  = i >> 4;
            int kk = i & 15;
            int rg = row0 + r;
            xs[kk][r] = (rg < N_NODES) ? x[(size_t)rg * D + k0 + kk] : 0.0f;
        }
#pragma unroll
        for (int j = 0; j < 4; j++) {
            int i  = t + j * 256;
            int c  = i >> 4;
            int kk = i & 15;
            wt[kk][c] = W[(size_t)(col0 + c) * D + k0 + kk];
        }
        __syncthreads();
#pragma unroll
        for (int kk = 0; kk < 16; kk++) {
            float a_[4], b_[4];
#pragma unroll
            for (int i = 0; i < 4; i++) a_[i] = xs[kk][ty * 4 + i];
#pragma unroll
            for (int j = 0; j < 4; j++) b_[j] = wt[kk][tx * 4 + j];
#pragma unroll
            for (int i = 0; i < 4; i++)
#pragma unroll
                for (int j = 0; j < 4; j++) acc[i][j] += a_[i] * b_[j];
        }
        __syncthreads();
    }
#pragma unroll
    for (int i = 0; i < 4; i++) {
        int r = row0 + ty * 4 + i;
        if (r < N_NODES) {
#pragma unroll
            for (int j = 0; j < 4; j++)
                h[(size_t)r * D + col0 + tx * 4 + j] = acc[i][j];
        }
    }
}

// ---------------------------------------------------------------------------
// 5. Gather-reduce + self-loop + bias + alpha blend. One wave per dst node.
//    lane owns columns [lane*4, lane*4+4)
// ---------------------------------------------------------------------------
__global__ __launch_bounds__(256) void gather_kernel(const int* __restrict__ row_ptr,
                                                     const int* __restrict__ csr_src,
                                                     const float* __restrict__ dinv,
                                                     const float* __restrict__ h,
                                                     const float* __restrict__ x,
                                                     const float* __restrict__ b,
                                                     const float* __restrict__ alpha,
                                                     float* __restrict__ out) {
    int n    = blockIdx.x * 4 + (threadIdx.x >> 6);
    int lane = threadIdx.x & 63;
    if (n >= N_NODES) return;

    const int beg = row_ptr[n];
    const int end = row_ptr[n + 1];
    const float dn = dinv[n];

    float4 acc = make_float4(0.f, 0.f, 0.f, 0.f);
    int k = beg;
    for (; k + 1 < end; k += 2) {
        int s0 = csr_src[k];
        int s1 = csr_src[k + 1];
        float n0 = dinv[s0] * dn;
        float n1 = dinv[s1] * dn;
        float4 h0 = *reinterpret_cast<const float4*>(&h[(size_t)s0 * D + lane * 4]);
        float4 h1 = *reinterpret_cast<const float4*>(&h[(size_t)s1 * D + lane * 4]);
        acc.x += h0.x * n0 + h1.x * n1;
        acc.y += h0.y * n0 + h1.y * n1;
        acc.z += h0.z * n0 + h1.z * n1;
        acc.w += h0.w * n0 + h1.w * n1;
    }
    if (k < end) {
        int s0 = csr_src[k];
        float n0 = dinv[s0] * dn;
        float4 h0 = *reinterpret_cast<const float4*>(&h[(size_t)s0 * D + lane * 4]);
        acc.x += h0.x * n0;
        acc.y += h0.y * n0;
        acc.z += h0.z * n0;
        acc.w += h0.w * n0;
    }

    // self-loop + bias + blend: out = a*x + (1-a)*(acc + dn^2*h[n] + b)
    float dv2 = dn * dn;
    float a   = alpha[0];
    float4 hv = *reinterpret_cast<const float4*>(&h[(size_t)n * D + lane * 4]);
    float4 xv = *reinterpret_cast<const float4*>(&x[(size_t)n * D + lane * 4]);
    float4 bv = *reinterpret_cast<const float4*>(&b[lane * 4]);
    float4 r;
    r.x = a * xv.x + (1.0f - a) * (acc.x + dv2 * hv.x + bv.x);
    r.y = a * xv.y + (1.0f - a) * (acc.y + dv2 * hv.y + bv.y);
    r.z = a * xv.z + (1.0f - a) * (acc.z + dv2 * hv.z + bv.z);
    r.w = a * xv.w + (1.0f - a) * (acc.w + dv2 * hv.w + bv.w);
    *reinterpret_cast<float4*>(&out[(size_t)n * D + lane * 4]) = r;
}

// ---------------------------------------------------------------------------
extern "C" void kernel_launch(void* const* d_in, const int* in_sizes, int n_in,
                              void* d_out, int out_size, void* d_ws, size_t ws_size,
                              hipStream_t stream) {
    const float* x     = (const float*)d_in[0];
    const int*   ei    = (const int*)d_in[1];
    const float* W     = (const float*)d_in[2];
    const float* b     = (const float*)d_in[3];
    const float* alpha = (const float*)d_in[4];
    float* out = (float*)d_out;

    char* ws = (char*)d_ws;
    const size_t HB = (size_t)N_NODES * D * 4;  // 51,200,000
    float* h       = (float*)ws;
    int*   deg     = (int*)(ws + HB);                       // 200,000 B
    int*   row_ptr = (int*)(ws + HB + 200000);              // 200,016 B (N+1)
    int*   cursor  = (int*)(ws + HB + 400016);              // 200,000 B
    float* dinv    = (float*)(ws + HB + 600016);            // 200,000 B
    int*   csr_src = (int*)(ws + HB + 800016);              // 3,200,000 B

    hipMemsetAsync(deg, 0, (size_t)N_NODES * 4, stream);

    deg_kernel<<<(N_EDGES + 255) / 256, 256, 0, stream>>>(ei, deg);
    scan_kernel<<<1, 1024, 0, stream>>>(deg, row_ptr, cursor, dinv);
    fill_kernel<<<(N_EDGES + 255) / 256, 256, 0, stream>>>(ei, cursor, csr_src);
    gemm_kernel<<<dim3((N_NODES + 63) / 64, D / 64), 256, 0, stream>>>(x, W, h);
    gather_kernel<<<(N_NODES + 3) / 4, 256, 0, stream>>>(row_ptr, csr_src, dinv, h, x, b, alpha, out);
}

// Round 4
// 243.378 us; speedup vs baseline: 11.8694x; 1.8909x over previous
//
#include <hip/hip_runtime.h>

#define N_NODES 50000
#define N_EDGES 800000
#define D 256
#define SCAN_BLOCKS 49   // ceil(50000/1024)

typedef unsigned short bf16_t;
typedef __attribute__((ext_vector_type(8))) short short8;
typedef __attribute__((ext_vector_type(4))) float f32x4;

__device__ inline float b2f(bf16_t u) {
    union { float f; unsigned v; } t; t.v = ((unsigned)u) << 16; return t.f;
}
__device__ inline bf16_t f2b(float f) {
    union { float f; unsigned v; } t; t.f = f;
    unsigned u = t.v;
    unsigned r = (u + 0x7FFFu + ((u >> 16) & 1u)) >> 16;   // RNE
    return (bf16_t)r;
}

// ---------------------------------------------------------------------------
// 1. Degree histogram over edge destinations.
// ---------------------------------------------------------------------------
__global__ void deg_kernel(const int* __restrict__ ei, int* __restrict__ deg) {
    int e = blockIdx.x * blockDim.x + threadIdx.x;
    if (e < N_EDGES) {
        int d = ei[N_EDGES + e];
        if ((unsigned)d < (unsigned)N_NODES) atomicAdd(&deg[d], 1);
    }
}

// ---------------------------------------------------------------------------
// 2a. Block-local exclusive scan (wave shuffle based). loc = local exclusive.
// ---------------------------------------------------------------------------
__global__ __launch_bounds__(1024) void scan1_kernel(const int* __restrict__ deg,
                                                     int* __restrict__ loc,
                                                     int* __restrict__ blk_sum) {
    int i = blockIdx.x * 1024 + threadIdx.x;
    int v = (i < N_NODES) ? deg[i] : 0;
    int lane = threadIdx.x & 63;
    int wid  = threadIdx.x >> 6;  // 0..15
    int s = v;
#pragma unroll
    for (int off = 1; off < 64; off <<= 1) {
        int t = __shfl_up(s, off, 64);
        if (lane >= off) s += t;
    }
    __shared__ int wsum[16];
    if (lane == 63) wsum[wid] = s;
    __syncthreads();
    if (threadIdx.x < 16) {
        int ws = wsum[threadIdx.x];
        int t0 = ws;
#pragma unroll
        for (int off = 1; off < 16; off <<= 1) {
            int t = __shfl_up(t0, off, 64);
            if ((int)threadIdx.x >= off) t0 += t;
        }
        wsum[threadIdx.x] = t0 - ws;  // exclusive wave offset
        if (threadIdx.x == 15) blk_sum[blockIdx.x] = t0;
    }
    __syncthreads();
    if (i < N_NODES) loc[i] = wsum[wid] + s - v;
}

// ---------------------------------------------------------------------------
// 2b. Scan the 49 block sums in one wave.
// ---------------------------------------------------------------------------
__global__ void scan2_kernel(const int* __restrict__ blk_sum, int* __restrict__ blk_off) {
    int lane = threadIdx.x;  // 64 threads
    int v = (lane < SCAN_BLOCKS) ? blk_sum[lane] : 0;
    int s = v;
#pragma unroll
    for (int off = 1; off < 64; off <<= 1) {
        int t = __shfl_up(s, off, 64);
        if (lane >= off) s += t;
    }
    if (lane < SCAN_BLOCKS) blk_off[lane] = s - v;
    if (lane == SCAN_BLOCKS - 1) blk_off[SCAN_BLOCKS] = s;  // total
}

// ---------------------------------------------------------------------------
// 2c. Apply block offsets; emit row_ptr, cursor, dinv.  (loc aliases cursor)
// ---------------------------------------------------------------------------
__global__ __launch_bounds__(1024) void scan3_kernel(int* __restrict__ loc_cursor,
                                                     const int* __restrict__ blk_off,
                                                     const int* __restrict__ deg,
                                                     int* __restrict__ row_ptr,
                                                     float* __restrict__ dinv) {
    int i = blockIdx.x * 1024 + threadIdx.x;
    if (i < N_NODES) {
        int rp = loc_cursor[i] + blk_off[blockIdx.x];
        row_ptr[i] = rp;
        loc_cursor[i] = rp;  // becomes cursor
        dinv[i] = rsqrtf((float)(deg[i] + 1));
    }
    if (i == 0) row_ptr[N_NODES] = blk_off[SCAN_BLOCKS];
}

// ---------------------------------------------------------------------------
// 3. Bucket fill: csr_src[pos] = src for each edge, bucketed by dst.
// ---------------------------------------------------------------------------
__global__ void fill_kernel(const int* __restrict__ ei, int* __restrict__ cursor,
                            int* __restrict__ csr_src) {
    int e = blockIdx.x * blockDim.x + threadIdx.x;
    if (e < N_EDGES) {
        int s = ei[e];
        int d = ei[N_EDGES + e];
        if ((unsigned)d < (unsigned)N_NODES) {
            int pos = atomicAdd(&cursor[d], 1);
            csr_src[pos] = s;
        }
    }
}

// ---------------------------------------------------------------------------
// 4. fp32 -> bf16 convert (float4 in, 4x bf16 out)
// ---------------------------------------------------------------------------
__global__ void cvt_kernel(const float* __restrict__ in, bf16_t* __restrict__ out, int n4) {
    int i = blockIdx.x * blockDim.x + threadIdx.x;
    if (i >= n4) return;
    float4 v = reinterpret_cast<const float4*>(in)[i];
    ushort4 o;
    o.x = f2b(v.x);
    o.y = f2b(v.y);
    o.z = f2b(v.z);
    o.w = f2b(v.w);
    reinterpret_cast<ushort4*>(out)[i] = o;
}

// ---------------------------------------------------------------------------
// 5. h = x @ W^T in bf16 MFMA. 128x128 block tile, 4 waves (2x2), each wave
//    64x64 = 4x4 fragments of 16x16x32. Fragments loaded straight from
//    global (L1/L2-resident); no LDS.
//    A[i][k]: lane l holds row i=l&15, k = (l>>4)*8 + b (contiguous 8, 16B)
//    B[k][j]: lane l holds col j=l&15, k = (l>>4)*8 + b
//    D[i][j]: col = l&15, row = (l>>4)*4 + reg        (m89-verified)
// ---------------------------------------------------------------------------
__global__ __launch_bounds__(256) void mfma_gemm_kernel(const bf16_t* __restrict__ xb,
                                                        const bf16_t* __restrict__ Wb,
                                                        bf16_t* __restrict__ h) {
    const int wid  = threadIdx.x >> 6;   // 0..3
    const int lane = threadIdx.x & 63;
    const int wr = wid >> 1;             // wave row 0..1
    const int wc = wid & 1;              // wave col 0..1
    const int row0 = blockIdx.x * 128 + wr * 64;
    const int col0 = blockIdx.y * 128 + wc * 64;
    const int lr = lane & 15;
    const int lk = (lane >> 4) * 8;

    f32x4 acc[4][4] = {};

    for (int k0 = 0; k0 < D; k0 += 32) {
        short8 a[4], b[4];
#pragma unroll
        for (int m = 0; m < 4; m++) {
            int r = row0 + m * 16 + lr;
            if (r >= N_NODES) r = N_NODES - 1;  // clamp; store is guarded
            a[m] = *reinterpret_cast<const short8*>(&xb[(size_t)r * D + k0 + lk]);
        }
#pragma unroll
        for (int n = 0; n < 4; n++) {
            int c = col0 + n * 16 + lr;
            b[n] = *reinterpret_cast<const short8*>(&Wb[(size_t)c * D + k0 + lk]);
        }
#pragma unroll
        for (int m = 0; m < 4; m++)
#pragma unroll
            for (int n = 0; n < 4; n++)
                acc[m][n] = __builtin_amdgcn_mfma_f32_16x16x32_bf16(a[m], b[n], acc[m][n], 0, 0, 0);
    }

#pragma unroll
    for (int m = 0; m < 4; m++) {
        int rbase = row0 + m * 16 + (lane >> 4) * 4;
#pragma unroll
        for (int j = 0; j < 4; j++) {
            int r = rbase + j;
            if (r < N_NODES) {
#pragma unroll
                for (int n = 0; n < 4; n++) {
                    int c = col0 + n * 16 + lr;
                    h[(size_t)r * D + c] = f2b(acc[m][n][j]);
                }
            }
        }
    }
}

// ---------------------------------------------------------------------------
// 6. Gather-reduce + self-loop + bias + alpha blend. One wave per dst node.
//    h is bf16; lane owns 4 columns (8B loads).
// ---------------------------------------------------------------------------
__global__ __launch_bounds__(256) void gather_kernel(const int* __restrict__ row_ptr,
                                                     const int* __restrict__ csr_src,
                                                     const float* __restrict__ dinv,
                                                     const bf16_t* __restrict__ h,
                                                     const float* __restrict__ x,
                                                     const float* __restrict__ b,
                                                     const float* __restrict__ alpha,
                                                     float* __restrict__ out) {
    int n    = blockIdx.x * 4 + (threadIdx.x >> 6);
    int lane = threadIdx.x & 63;
    if (n >= N_NODES) return;

    const int beg = row_ptr[n];
    const int end = row_ptr[n + 1];
    const float dn = dinv[n];

    float ax = 0.f, ay = 0.f, az = 0.f, aw = 0.f;
    int k = beg;
    for (; k + 1 < end; k += 2) {
        int s0 = csr_src[k];
        int s1 = csr_src[k + 1];
        float n0 = dinv[s0] * dn;
        float n1 = dinv[s1] * dn;
        ushort4 h0 = *reinterpret_cast<const ushort4*>(&h[(size_t)s0 * D + lane * 4]);
        ushort4 h1 = *reinterpret_cast<const ushort4*>(&h[(size_t)s1 * D + lane * 4]);
        ax += b2f(h0.x) * n0 + b2f(h1.x) * n1;
        ay += b2f(h0.y) * n0 + b2f(h1.y) * n1;
        az += b2f(h0.z) * n0 + b2f(h1.z) * n1;
        aw += b2f(h0.w) * n0 + b2f(h1.w) * n1;
    }
    if (k < end) {
        int s0 = csr_src[k];
        float n0 = dinv[s0] * dn;
        ushort4 h0 = *reinterpret_cast<const ushort4*>(&h[(size_t)s0 * D + lane * 4]);
        ax += b2f(h0.x) * n0;
        ay += b2f(h0.y) * n0;
        az += b2f(h0.z) * n0;
        aw += b2f(h0.w) * n0;
    }

    float dv2 = dn * dn;
    float a   = alpha[0];
    ushort4 hv = *reinterpret_cast<const ushort4*>(&h[(size_t)n * D + lane * 4]);
    float4  xv = *reinterpret_cast<const float4*>(&x[(size_t)n * D + lane * 4]);
    float4  bv = *reinterpret_cast<const float4*>(&b[lane * 4]);
    float4 r;
    r.x = a * xv.x + (1.0f - a) * (ax + dv2 * b2f(hv.x) + bv.x);
    r.y = a * xv.y + (1.0f - a) * (ay + dv2 * b2f(hv.y) + bv.y);
    r.z = a * xv.z + (1.0f - a) * (az + dv2 * b2f(hv.z) + bv.z);
    r.w = a * xv.w + (1.0f - a) * (aw + dv2 * b2f(hv.w) + bv.w);
    *reinterpret_cast<float4*>(&out[(size_t)n * D + lane * 4]) = r;
}

// ---------------------------------------------------------------------------
extern "C" void kernel_launch(void* const* d_in, const int* in_sizes, int n_in,
                              void* d_out, int out_size, void* d_ws, size_t ws_size,
                              hipStream_t stream) {
    const float* x     = (const float*)d_in[0];
    const int*   ei    = (const int*)d_in[1];
    const float* W     = (const float*)d_in[2];
    const float* b     = (const float*)d_in[3];
    const float* alpha = (const float*)d_in[4];
    float* out = (float*)d_out;

    char* ws = (char*)d_ws;
    const size_t HB = (size_t)N_NODES * D * 2;  // 25,600,000
    bf16_t* h   = (bf16_t*)ws;
    bf16_t* xb  = (bf16_t*)(ws + HB);
    bf16_t* Wb  = (bf16_t*)(ws + 2 * HB);                            // 131,072 B
    int*   deg     = (int*)  (ws + 2 * HB + 131072);                 // 200,000
    int*   row_ptr = (int*)  (ws + 2 * HB + 131072 + 200000);        // 200,016 (N+1, padded)
    int*   cursor  = (int*)  (ws + 2 * HB + 131072 + 400016);        // 200,000 (aliases loc)
    float* dinv    = (float*)(ws + 2 * HB + 131072 + 600016);        // 200,000
    int*   blk_sum = (int*)  (ws + 2 * HB + 131072 + 800016);        // 256
    int*   blk_off = (int*)  (ws + 2 * HB + 131072 + 800272);        // 256
    int*   csr_src = (int*)  (ws + 2 * HB + 131072 + 800528);        // 3,200,000

    (void)hipMemsetAsync(deg, 0, (size_t)N_NODES * 4, stream);

    deg_kernel<<<(N_EDGES + 255) / 256, 256, 0, stream>>>(ei, deg);
    scan1_kernel<<<SCAN_BLOCKS, 1024, 0, stream>>>(deg, cursor, blk_sum);
    scan2_kernel<<<1, 64, 0, stream>>>(blk_sum, blk_off);
    scan3_kernel<<<SCAN_BLOCKS, 1024, 0, stream>>>(cursor, blk_off, deg, row_ptr, dinv);
    fill_kernel<<<(N_EDGES + 255) / 256, 256, 0, stream>>>(ei, cursor, csr_src);

    cvt_kernel<<<(N_NODES * D / 4 + 255) / 256, 256, 0, stream>>>(x, xb, N_NODES * D / 4);
    cvt_kernel<<<(D * D / 4 + 255) / 256, 256, 0, stream>>>(W, Wb, D * D / 4);

    mfma_gemm_kernel<<<dim3((N_NODES + 127) / 128, D / 128), 256, 0, stream>>>(xb, Wb, h);

    gather_kernel<<<(N_NODES + 3) / 4, 256, 0, stream>>>(row_ptr, csr_src, dinv, h, x, b, alpha, out);
}

// Round 5
// 239.434 us; speedup vs baseline: 12.0648x; 1.0165x over previous
//
#include <hip/hip_runtime.h>

#define N_NODES 50000
#define N_EDGES 800000
#define D 256
#define SCAN_BLOCKS 49   // ceil(50000/1024)

typedef unsigned short bf16_t;
typedef __attribute__((ext_vector_type(8))) short short8;
typedef __attribute__((ext_vector_type(4))) float f32x4;

__device__ inline float b2f(bf16_t u) {
    union { float f; unsigned v; } t; t.v = ((unsigned)u) << 16; return t.f;
}
__device__ inline bf16_t f2b(float f) {
    union { float f; unsigned v; } t; t.f = f;
    unsigned u = t.v;
    unsigned r = (u + 0x7FFFu + ((u >> 16) & 1u)) >> 16;   // RNE
    return (bf16_t)r;
}
// packed f32x2 -> bf16x2 (low word = first arg), HW RNE
__device__ inline unsigned cvt_pk_bf16(float lo, float hi) {
    unsigned r;
    asm("v_cvt_pk_bf16_f32 %0, %1, %2" : "=v"(r) : "v"(lo), "v"(hi));
    return r;
}
__device__ inline short8 cvt8(float4 a, float4 b) {
    union { short8 s; unsigned u[4]; } t;
    t.u[0] = cvt_pk_bf16(a.x, a.y);
    t.u[1] = cvt_pk_bf16(a.z, a.w);
    t.u[2] = cvt_pk_bf16(b.x, b.y);
    t.u[3] = cvt_pk_bf16(b.z, b.w);
    return t.s;
}

// ---------------------------------------------------------------------------
// 1. Degree histogram over edge destinations.
// ---------------------------------------------------------------------------
__global__ void deg_kernel(const int* __restrict__ ei, int* __restrict__ deg) {
    int e = blockIdx.x * blockDim.x + threadIdx.x;
    if (e < N_EDGES) {
        int d = ei[N_EDGES + e];
        if ((unsigned)d < (unsigned)N_NODES) atomicAdd(&deg[d], 1);
    }
}

// ---------------------------------------------------------------------------
// 2a. Block-local exclusive scan (wave shuffle based). loc = local exclusive.
// ---------------------------------------------------------------------------
__global__ __launch_bounds__(1024) void scan1_kernel(const int* __restrict__ deg,
                                                     int* __restrict__ loc,
                                                     int* __restrict__ blk_sum) {
    int i = blockIdx.x * 1024 + threadIdx.x;
    int v = (i < N_NODES) ? deg[i] : 0;
    int lane = threadIdx.x & 63;
    int wid  = threadIdx.x >> 6;  // 0..15
    int s = v;
#pragma unroll
    for (int off = 1; off < 64; off <<= 1) {
        int t = __shfl_up(s, off, 64);
        if (lane >= off) s += t;
    }
    __shared__ int wsum[16];
    if (lane == 63) wsum[wid] = s;
    __syncthreads();
    if (threadIdx.x < 16) {
        int ws = wsum[threadIdx.x];
        int t0 = ws;
#pragma unroll
        for (int off = 1; off < 16; off <<= 1) {
            int t = __shfl_up(t0, off, 64);
            if ((int)threadIdx.x >= off) t0 += t;
        }
        wsum[threadIdx.x] = t0 - ws;  // exclusive wave offset
        if (threadIdx.x == 15) blk_sum[blockIdx.x] = t0;
    }
    __syncthreads();
    if (i < N_NODES) loc[i] = wsum[wid] + s - v;
}

// ---------------------------------------------------------------------------
// 2b. Scan the 49 block sums in one wave.
// ---------------------------------------------------------------------------
__global__ void scan2_kernel(const int* __restrict__ blk_sum, int* __restrict__ blk_off) {
    int lane = threadIdx.x;  // 64 threads
    int v = (lane < SCAN_BLOCKS) ? blk_sum[lane] : 0;
    int s = v;
#pragma unroll
    for (int off = 1; off < 64; off <<= 1) {
        int t = __shfl_up(s, off, 64);
        if (lane >= off) s += t;
    }
    if (lane < SCAN_BLOCKS) blk_off[lane] = s - v;
    if (lane == SCAN_BLOCKS - 1) blk_off[SCAN_BLOCKS] = s;  // total
}

// ---------------------------------------------------------------------------
// 2c. Apply block offsets; emit row_ptr, cursor, dinv.  (loc aliases cursor)
// ---------------------------------------------------------------------------
__global__ __launch_bounds__(1024) void scan3_kernel(int* __restrict__ loc_cursor,
                                                     const int* __restrict__ blk_off,
                                                     const int* __restrict__ deg,
                                                     int* __restrict__ row_ptr,
                                                     float* __restrict__ dinv) {
    int i = blockIdx.x * 1024 + threadIdx.x;
    if (i < N_NODES) {
        int rp = loc_cursor[i] + blk_off[blockIdx.x];
        row_ptr[i] = rp;
        loc_cursor[i] = rp;  // becomes cursor
        dinv[i] = rsqrtf((float)(deg[i] + 1));
    }
    if (i == 0) row_ptr[N_NODES] = blk_off[SCAN_BLOCKS];
}

// ---------------------------------------------------------------------------
// 3. Bucket fill: csr_src[pos] = src for each edge, bucketed by dst.
// ---------------------------------------------------------------------------
__global__ void fill_kernel(const int* __restrict__ ei, int* __restrict__ cursor,
                            int* __restrict__ csr_src) {
    int e = blockIdx.x * blockDim.x + threadIdx.x;
    if (e < N_EDGES) {
        int s = ei[e];
        int d = ei[N_EDGES + e];
        if ((unsigned)d < (unsigned)N_NODES) {
            int pos = atomicAdd(&cursor[d], 1);
            csr_src[pos] = s;
        }
    }
}

// ---------------------------------------------------------------------------
// 4. h = x @ W^T, fp32 in / bf16 MFMA / bf16 out, conversion fused in-kernel.
//    128 rows x 256 cols per block, 512 thr = 8 waves (2 wr x 4 wc),
//    each wave 64x64 = 4x4 fragments of 16x16x32. No LDS; frags from L1/L2.
//    A[i][k]: lane l holds row i=l&15, k = (l>>4)*8 + b (32B fp32 -> cvt_pk)
//    B[k][j]: lane l holds col j=l&15, k = (l>>4)*8 + b
//    D[i][j]: col = l&15, row = (l>>4)*4 + reg        (m89-verified)
// ---------------------------------------------------------------------------
__global__ __launch_bounds__(512) void mfma_gemm_kernel(const float* __restrict__ x,
                                                        const float* __restrict__ W,
                                                        bf16_t* __restrict__ h) {
    const int wid  = threadIdx.x >> 6;   // 0..7
    const int lane = threadIdx.x & 63;
    const int wr = wid >> 2;             // 0..1
    const int wc = wid & 3;              // 0..3
    const int row0 = blockIdx.x * 128 + wr * 64;
    const int col0 = wc * 64;
    const int lr = lane & 15;
    const int lk = (lane >> 4) * 8;

    f32x4 acc[4][4] = {};

    for (int k0 = 0; k0 < D; k0 += 32) {
        short8 a[4], b[4];
#pragma unroll
        for (int m = 0; m < 4; m++) {
            int r = row0 + m * 16 + lr;
            if (r >= N_NODES) r = N_NODES - 1;  // clamp; store is guarded
            const float4* p = reinterpret_cast<const float4*>(&x[(size_t)r * D + k0 + lk]);
            a[m] = cvt8(p[0], p[1]);
        }
#pragma unroll
        for (int n = 0; n < 4; n++) {
            int c = col0 + n * 16 + lr;
            const float4* p = reinterpret_cast<const float4*>(&W[(size_t)c * D + k0 + lk]);
            b[n] = cvt8(p[0], p[1]);
        }
#pragma unroll
        for (int m = 0; m < 4; m++)
#pragma unroll
            for (int n = 0; n < 4; n++)
                acc[m][n] = __builtin_amdgcn_mfma_f32_16x16x32_bf16(a[m], b[n], acc[m][n], 0, 0, 0);
    }

#pragma unroll
    for (int m = 0; m < 4; m++) {
        int rbase = row0 + m * 16 + (lane >> 4) * 4;
#pragma unroll
        for (int j = 0; j < 4; j++) {
            int r = rbase + j;
            if (r < N_NODES) {
#pragma unroll
                for (int n = 0; n < 4; n++) {
                    int c = col0 + n * 16 + lr;
                    h[(size_t)r * D + c] = f2b(acc[m][n][j]);
                }
            }
        }
    }
}

// ---------------------------------------------------------------------------
// 5. Gather-reduce + self-loop + bias + alpha blend. One wave per dst node.
//    h is bf16; lane owns 4 columns (8B loads). Unroll-4 for MLP.
// ---------------------------------------------------------------------------
__global__ __launch_bounds__(256) void gather_kernel(const int* __restrict__ row_ptr,
                                                     const int* __restrict__ csr_src,
                                                     const float* __restrict__ dinv,
                                                     const bf16_t* __restrict__ h,
                                                     const float* __restrict__ x,
                                                     const float* __restrict__ b,
                                                     const float* __restrict__ alpha,
                                                     float* __restrict__ out) {
    int n    = blockIdx.x * 4 + (threadIdx.x >> 6);
    int lane = threadIdx.x & 63;
    if (n >= N_NODES) return;

    const int beg = row_ptr[n];
    const int end = row_ptr[n + 1];
    const float dn = dinv[n];
    const bf16_t* hl = h + (size_t)lane * 4;

    float ax = 0.f, ay = 0.f, az = 0.f, aw = 0.f;
    int k = beg;
    for (; k + 3 < end; k += 4) {
        int s0 = csr_src[k];
        int s1 = csr_src[k + 1];
        int s2 = csr_src[k + 2];
        int s3 = csr_src[k + 3];
        float n0 = dinv[s0] * dn;
        float n1 = dinv[s1] * dn;
        float n2 = dinv[s2] * dn;
        float n3 = dinv[s3] * dn;
        ushort4 h0 = *reinterpret_cast<const ushort4*>(&hl[(size_t)s0 * D]);
        ushort4 h1 = *reinterpret_cast<const ushort4*>(&hl[(size_t)s1 * D]);
        ushort4 h2 = *reinterpret_cast<const ushort4*>(&hl[(size_t)s2 * D]);
        ushort4 h3 = *reinterpret_cast<const ushort4*>(&hl[(size_t)s3 * D]);
        ax += b2f(h0.x) * n0 + b2f(h1.x) * n1 + b2f(h2.x) * n2 + b2f(h3.x) * n3;
        ay += b2f(h0.y) * n0 + b2f(h1.y) * n1 + b2f(h2.y) * n2 + b2f(h3.y) * n3;
        az += b2f(h0.z) * n0 + b2f(h1.z) * n1 + b2f(h2.z) * n2 + b2f(h3.z) * n3;
        aw += b2f(h0.w) * n0 + b2f(h1.w) * n1 + b2f(h2.w) * n2 + b2f(h3.w) * n3;
    }
    for (; k < end; k++) {
        int s0 = csr_src[k];
        float n0 = dinv[s0] * dn;
        ushort4 h0 = *reinterpret_cast<const ushort4*>(&hl[(size_t)s0 * D]);
        ax += b2f(h0.x) * n0;
        ay += b2f(h0.y) * n0;
        az += b2f(h0.z) * n0;
        aw += b2f(h0.w) * n0;
    }

    float dv2 = dn * dn;
    float a   = alpha[0];
    ushort4 hv = *reinterpret_cast<const ushort4*>(&hl[(size_t)n * D]);
    float4  xv = *reinterpret_cast<const float4*>(&x[(size_t)n * D + lane * 4]);
    float4  bv = *reinterpret_cast<const float4*>(&b[lane * 4]);
    float4 r;
    r.x = a * xv.x + (1.0f - a) * (ax + dv2 * b2f(hv.x) + bv.x);
    r.y = a * xv.y + (1.0f - a) * (ay + dv2 * b2f(hv.y) + bv.y);
    r.z = a * xv.z + (1.0f - a) * (az + dv2 * b2f(hv.z) + bv.z);
    r.w = a * xv.w + (1.0f - a) * (aw + dv2 * b2f(hv.w) + bv.w);
    *reinterpret_cast<float4*>(&out[(size_t)n * D + lane * 4]) = r;
}

// ---------------------------------------------------------------------------
extern "C" void kernel_launch(void* const* d_in, const int* in_sizes, int n_in,
                              void* d_out, int out_size, void* d_ws, size_t ws_size,
                              hipStream_t stream) {
    const float* x     = (const float*)d_in[0];
    const int*   ei    = (const int*)d_in[1];
    const float* W     = (const float*)d_in[2];
    const float* b     = (const float*)d_in[3];
    const float* alpha = (const float*)d_in[4];
    float* out = (float*)d_out;

    char* ws = (char*)d_ws;
    const size_t HB = (size_t)N_NODES * D * 2;  // 25,600,000
    bf16_t* h      = (bf16_t*)ws;
    int*   deg     = (int*)  (ws + HB);                 // 200,000
    int*   row_ptr = (int*)  (ws + HB + 200000);        // 200,016 (N+1, padded)
    int*   cursor  = (int*)  (ws + HB + 400016);        // 200,000 (aliases loc)
    float* dinv    = (float*)(ws + HB + 600016);        // 200,000
    int*   blk_sum = (int*)  (ws + HB + 800016);        // 256
    int*   blk_off = (int*)  (ws + HB + 800272);        // 256
    int*   csr_src = (int*)  (ws + HB + 800528);        // 3,200,000

    (void)hipMemsetAsync(deg, 0, (size_t)N_NODES * 4, stream);

    deg_kernel<<<(N_EDGES + 255) / 256, 256, 0, stream>>>(ei, deg);
    scan1_kernel<<<SCAN_BLOCKS, 1024, 0, stream>>>(deg, cursor, blk_sum);
    scan2_kernel<<<1, 64, 0, stream>>>(blk_sum, blk_off);
    scan3_kernel<<<SCAN_BLOCKS, 1024, 0, stream>>>(cursor, blk_off, deg, row_ptr, dinv);
    fill_kernel<<<(N_EDGES + 255) / 256, 256, 0, stream>>>(ei, cursor, csr_src);

    mfma_gemm_kernel<<<(N_NODES + 127) / 128, 512, 0, stream>>>(x, W, h);

    gather_kernel<<<(N_NODES + 3) / 4, 256, 0, stream>>>(row_ptr, csr_src, dinv, h, x, b, alpha, out);
}